// Round 1
// baseline (1486.670 us; speedup 1.0000x reference)
//
#include <hip/hip_runtime.h>

// CrossOp: ox = conv3x3(x, wx)+bias ; oy_s = conv3x3(y_s, wy)
// interaction[b,s] = leaky(ox[b] + oy[b,s]) ; new_target = mean_s(interaction)
// Shapes: x(4,1,16,128,128) y(4,32,16,128,128) w(64,32,3,3) bias(64)
// out = [new_target (4,1,64,128,128) | interaction (4,32,64,128,128)], fp32.

#define NEG_SLOPE 0.01f

constexpr int Bn = 4, Sy = 32, Ci = 16, Co = 64, Hh = 128, Ww = 128;
constexpr int TH = 4, TW = 64;          // spatial tile: 4 rows x 64 cols
constexpr int HHALO = TH + 2;           // 6
constexpr int WHALO = TW + 2;           // 66
constexpr int NCO = 32;                 // co per block (2 co-blocks)
constexpr int STAGE_N = Ci * HHALO * WHALO;  // 6336 floats = 25.3 KB

__global__ __launch_bounds__(256, 2)
void crossop_kernel(const float* __restrict__ x,
                    const float* __restrict__ y,
                    const float* __restrict__ wgt,
                    const float* __restrict__ bias,
                    float* __restrict__ out)
{
    __shared__ float st[Ci][HHALO][WHALO];

    const int tile = blockIdx.x;            // 0..63 : 32 h-tiles x 2 w-tiles
    const int cob  = blockIdx.y;            // 0..1
    const int b    = blockIdx.z;            // 0..3
    const int th0  = (tile >> 1) * TH;
    const int tw0  = (tile & 1) * TW;
    const int tid  = threadIdx.x;
    const int py   = tid >> 6;              // wave-uniform row in tile (0..3)
    const int pw   = tid & 63;              // lane = col in tile (0..63)
    const int co0  = cob * NCO;

    float* ntgt  = out;                                        // (4,64,128,128)
    float* inter = out + (size_t)Bn * Co * Hh * Ww;            // (4,32,64,128,128)

    // ---------- stage x tile ----------
    {
        const float* xb = x + (size_t)b * Ci * Hh * Ww;
        for (int idx = tid; idx < STAGE_N; idx += 256) {
            int ci  = idx / (HHALO * WHALO);
            int rem = idx - ci * (HHALO * WHALO);
            int r   = rem / WHALO;
            int c   = rem - r * WHALO;
            int hh = th0 - 1 + r, ww = tw0 - 1 + c;
            float v = 0.f;
            if (hh >= 0 && hh < Hh && ww >= 0 && ww < Ww)
                v = xb[(size_t)ci * Hh * Ww + hh * Ww + ww];
            ((float*)st)[idx] = v;
        }
    }
    __syncthreads();

    // ---------- ox = conv(x, wx) + bias, kept in registers ----------
    float ox[NCO];
    #pragma unroll
    for (int j = 0; j < NCO; ++j) ox[j] = bias[co0 + j];

    for (int ci = 0; ci < Ci; ++ci) {
        #pragma unroll
        for (int kh = 0; kh < 3; ++kh)
        #pragma unroll
        for (int kw = 0; kw < 3; ++kw) {
            float v = st[ci][py + kh][pw + kw];
            #pragma unroll
            for (int j = 0; j < NCO; ++j)
                ox[j] += v * wgt[((co0 + j) * 32 + ci) * 9 + kh * 3 + kw];
        }
    }

    // ---------- loop over s: conv(y_s, wy), fuse add+leaky+mean ----------
    float msum[NCO];
    #pragma unroll
    for (int j = 0; j < NCO; ++j) msum[j] = 0.f;

    for (int s = 0; s < Sy; ++s) {
        __syncthreads();   // protect st before overwrite
        const float* yb = y + (size_t)(b * Sy + s) * Ci * Hh * Ww;
        for (int idx = tid; idx < STAGE_N; idx += 256) {
            int ci  = idx / (HHALO * WHALO);
            int rem = idx - ci * (HHALO * WHALO);
            int r   = rem / WHALO;
            int c   = rem - r * WHALO;
            int hh = th0 - 1 + r, ww = tw0 - 1 + c;
            float v = 0.f;
            if (hh >= 0 && hh < Hh && ww >= 0 && ww < Ww)
                v = yb[(size_t)ci * Hh * Ww + hh * Ww + ww];
            ((float*)st)[idx] = v;
        }
        __syncthreads();

        float acc[NCO];
        #pragma unroll
        for (int j = 0; j < NCO; ++j) acc[j] = ox[j];

        for (int ci = 0; ci < Ci; ++ci) {
            #pragma unroll
            for (int kh = 0; kh < 3; ++kh)
            #pragma unroll
            for (int kw = 0; kw < 3; ++kw) {
                float v = st[ci][py + kh][pw + kw];
                #pragma unroll
                for (int j = 0; j < NCO; ++j)
                    acc[j] += v * wgt[((co0 + j) * 32 + 16 + ci) * 9 + kh * 3 + kw];
            }
        }

        size_t obase = ((size_t)(b * Sy + s) * Co + co0) * (Hh * Ww)
                     + (size_t)(th0 + py) * Ww + tw0 + pw;
        #pragma unroll
        for (int j = 0; j < NCO; ++j) {
            float oz = acc[j];
            float r  = oz >= 0.f ? oz : NEG_SLOPE * oz;
            inter[obase + (size_t)j * Hh * Ww] = r;
            msum[j] += r;
        }
    }

    // ---------- mean over Sy ----------
    size_t nbase = ((size_t)b * Co + co0) * (Hh * Ww)
                 + (size_t)(th0 + py) * Ww + tw0 + pw;
    #pragma unroll
    for (int j = 0; j < NCO; ++j)
        ntgt[nbase + (size_t)j * Hh * Ww] = msum[j] * (1.f / 32.f);
}

extern "C" void kernel_launch(void* const* d_in, const int* in_sizes, int n_in,
                              void* d_out, int out_size, void* d_ws, size_t ws_size,
                              hipStream_t stream) {
    const float* x    = (const float*)d_in[0];
    const float* y    = (const float*)d_in[1];
    const float* wgt  = (const float*)d_in[2];
    const float* bias = (const float*)d_in[3];
    float* out = (float*)d_out;

    dim3 grid(64, 2, 4);   // 64 spatial tiles x 2 co-halves x 4 batches
    crossop_kernel<<<grid, 256, 0, stream>>>(x, y, wgt, bias, out);
}

// Round 2
// 186.113 us; speedup vs baseline: 7.9880x; 7.9880x over previous
//
#include <hip/hip_runtime.h>

// CrossOp via bf16 MFMA implicit-GEMM.
// out = [new_target (4,1,64,128,128) | interaction (4,32,64,128,128)], fp32.
// Per block: one (b, h) row, all 64 co. 4 waves; wave w owns co 16w..16w+15.
// K-order: k = shift*16 + ci, shift = kh*3+kw (0..8), K padded 144->160.
// LDS: [3 rows][130 w][16 ci (padded to 24)] bf16, double-buffered.

typedef __attribute__((ext_vector_type(8))) short short8;
typedef __attribute__((ext_vector_type(4))) float f32x4;
typedef __attribute__((ext_vector_type(4))) unsigned int u32x4;

__device__ __forceinline__ short to_bf16(float f) {
    unsigned u = __builtin_bit_cast(unsigned, f);
    u += 0x7fffu + ((u >> 16) & 1u);          // round-to-nearest-even
    return (short)(u >> 16);
}

constexpr int CIP      = 24;                  // ci pitch in shorts (48 B)
constexpr int ROWPITCH = 130 * CIP;           // 3120 shorts per input row slab
constexpr int BUFSH    = 3 * ROWPITCH;        // 9360 shorts per buffer

__global__ __launch_bounds__(256, 2)
void crossop_mfma(const float* __restrict__ xp, const float* __restrict__ yp,
                  const float* __restrict__ wp, const float* __restrict__ bp,
                  float* __restrict__ out)
{
    __shared__ __align__(16) short st[2][BUFSH];

    const int bid     = blockIdx.x;                     // 0..511
    const int logical = ((bid & 7) << 6) | (bid >> 3);  // XCD-chunked swizzle
    const int b       = logical >> 7;                   // 0..3
    const int h       = logical & 127;                  // output row
    const int tid  = threadIdx.x;
    const int lane = tid & 63;
    const int wid  = tid >> 6;
    const int q    = lane >> 4;        // quadrant 0..3
    const int mm   = lane & 15;
    const int co0  = wid << 4;         // wave's co base

    float* ntgt  = out;
    float* inter = out + (size_t)4 * 64 * 16384;

    // ---------------- zero LDS (halo cols / OOB rows stay 0) --------------
    {
        u32x4 zz = {0, 0, 0, 0};
        u32x4* z = (u32x4*)&st[0][0];
        const int nz = (2 * BUFSH * 2) / 16;   // 2340
        for (int i = tid; i < nz; i += 256) z[i] = zz;
    }

    // ---------------- weight fragments in registers (per wave: 16 co) ----
    short8 wx[5], wy[5];
    {
        const int co_a = co0 + mm;             // A-operand row = lane&15
        #pragma unroll
        for (int f = 0; f < 5; ++f) {
            #pragma unroll
            for (int j = 0; j < 8; ++j) {
                int k = f * 32 + q * 8 + j;    // k = (lane>>4)*8 + j within frag
                short vx = 0, vy = 0;
                if (k < 144) {
                    int sh = k >> 4, ci = k & 15;
                    vx = to_bf16(wp[(co_a * 32 + ci) * 9 + sh]);
                    vy = to_bf16(wp[(co_a * 32 + 16 + ci) * 9 + sh]);
                }
                wx[f][j] = vx;
                wy[f][j] = vy;
            }
        }
    }

    // per-lane B-fragment base offsets (short index), one per k-frag
    int Pf[5];
    #pragma unroll
    for (int f = 0; f < 5; ++f) {
        int sh = 2 * f + (q >> 1);
        if (sh > 8) sh = 8;                    // pad k: weights are 0, value dont-care
        int kh = sh / 3, kw = sh - kh * 3;
        Pf[f] = kh * ROWPITCH + (kw + mm) * CIP + ((q & 1) << 3);
    }

    float bias4[4];
    #pragma unroll
    for (int r = 0; r < 4; ++r) bias4[r] = bp[co0 + q * 4 + r];

    // staging decomposition: it -> input row (h+it-1); thread -> (ci-half, w)
    const int ch = (tid >> 7) & 1;             // ci half (0: ci 0..7, 1: 8..15)
    const int wv = tid & 127;                  // w column

    // ---------------- stage x into buf0 ----------------------------------
    {
        const float* src = xp + (size_t)b * 16 * 16384;
        float sr[3][8];
        #pragma unroll
        for (int it = 0; it < 3; ++it) {
            int hh = h + it - 1;
            bool valid = (unsigned)hh < 128u;
            const float* p = src + (size_t)(ch * 8) * 16384 + (size_t)hh * 128 + wv;
            #pragma unroll
            for (int c = 0; c < 8; ++c) sr[it][c] = valid ? p[(size_t)c * 16384] : 0.f;
        }
        #pragma unroll
        for (int it = 0; it < 3; ++it) {
            if ((unsigned)(h + it - 1) < 128u) {
                unsigned pk[4];
                #pragma unroll
                for (int c2 = 0; c2 < 4; ++c2)
                    pk[c2] = (unsigned)(unsigned short)to_bf16(sr[it][2 * c2]) |
                             ((unsigned)(unsigned short)to_bf16(sr[it][2 * c2 + 1]) << 16);
                *(u32x4*)&st[0][it * ROWPITCH + (wv + 1) * CIP + ch * 8] = *(u32x4*)pk;
            }
        }
    }
    __syncthreads();

    // ---------------- issue y(s=0) loads, compute ox, write y0 -> buf1 ---
    float sr[3][8];
    {
        const float* src = yp + (size_t)(b * 32 + 0) * 16 * 16384;
        #pragma unroll
        for (int it = 0; it < 3; ++it) {
            int hh = h + it - 1;
            bool valid = (unsigned)hh < 128u;
            const float* p = src + (size_t)(ch * 8) * 16384 + (size_t)hh * 128 + wv;
            #pragma unroll
            for (int c = 0; c < 8; ++c) sr[it][c] = valid ? p[(size_t)c * 16384] : 0.f;
        }
    }

    float ox[8][4];
    {
        const short* sb = st[0];
        #pragma unroll
        for (int t = 0; t < 8; ++t) {
            f32x4 acc = {bias4[0], bias4[1], bias4[2], bias4[3]};
            #pragma unroll
            for (int f = 0; f < 5; ++f) {
                short8 bb = *(const short8*)&sb[Pf[f] + t * 384];
                acc = __builtin_amdgcn_mfma_f32_16x16x32_bf16(wx[f], bb, acc, 0, 0, 0);
            }
            #pragma unroll
            for (int r = 0; r < 4; ++r) ox[t][r] = acc[r];
        }
    }

    // write y0 into buf1
    #pragma unroll
    for (int it = 0; it < 3; ++it) {
        if ((unsigned)(h + it - 1) < 128u) {
            unsigned pk[4];
            #pragma unroll
            for (int c2 = 0; c2 < 4; ++c2)
                pk[c2] = (unsigned)(unsigned short)to_bf16(sr[it][2 * c2]) |
                         ((unsigned)(unsigned short)to_bf16(sr[it][2 * c2 + 1]) << 16);
            *(u32x4*)&st[1][it * ROWPITCH + (wv + 1) * CIP + ch * 8] = *(u32x4*)pk;
        }
    }
    __syncthreads();

    // ---------------- s-loop: compute buf[(s+1)&1], prefetch s+1 ---------
    float msum[8][4];
    #pragma unroll
    for (int t = 0; t < 8; ++t)
        #pragma unroll
        for (int r = 0; r < 4; ++r) msum[t][r] = 0.f;

    for (int s = 0; s < 32; ++s) {
        const int rbuf = (s + 1) & 1;
        const int wbuf = s & 1;
        const bool pf = (s < 31);

        // T14: issue next-tile loads before the MFMA phase
        if (pf) {
            const float* src = yp + (size_t)(b * 32 + s + 1) * 16 * 16384;
            #pragma unroll
            for (int it = 0; it < 3; ++it) {
                int hh = h + it - 1;
                bool valid = (unsigned)hh < 128u;
                const float* p = src + (size_t)(ch * 8) * 16384 + (size_t)hh * 128 + wv;
                #pragma unroll
                for (int c = 0; c < 8; ++c) sr[it][c] = valid ? p[(size_t)c * 16384] : 0.f;
            }
        }

        // compute: per px-tile, acc = ox; 5 MFMAs; leaky + store + mean
        {
            const short* sb = st[rbuf];
            float* ibase = inter + ((size_t)(b * 32 + s) * 64 + co0 + q * 4) * 16384
                         + (size_t)h * 128;
            #pragma unroll
            for (int t = 0; t < 8; ++t) {
                f32x4 acc = {ox[t][0], ox[t][1], ox[t][2], ox[t][3]};
                #pragma unroll
                for (int f = 0; f < 5; ++f) {
                    short8 bb = *(const short8*)&sb[Pf[f] + t * 384];
                    acc = __builtin_amdgcn_mfma_f32_16x16x32_bf16(wy[f], bb, acc, 0, 0, 0);
                }
                #pragma unroll
                for (int r = 0; r < 4; ++r) {
                    float v = acc[r];
                    v = v >= 0.f ? v : 0.01f * v;
                    __builtin_nontemporal_store(v, ibase + (size_t)r * 16384 + t * 16 + mm);
                    msum[t][r] += v;
                }
            }
        }

        // write-late: cvt + ds_write of the prefetched tile
        if (pf) {
            #pragma unroll
            for (int it = 0; it < 3; ++it) {
                if ((unsigned)(h + it - 1) < 128u) {
                    unsigned pk[4];
                    #pragma unroll
                    for (int c2 = 0; c2 < 4; ++c2)
                        pk[c2] = (unsigned)(unsigned short)to_bf16(sr[it][2 * c2]) |
                                 ((unsigned)(unsigned short)to_bf16(sr[it][2 * c2 + 1]) << 16);
                    *(u32x4*)&st[wbuf][it * ROWPITCH + (wv + 1) * CIP + ch * 8] = *(u32x4*)pk;
                }
            }
        }
        __syncthreads();
    }

    // ---------------- mean over Sy --------------------------------------
    {
        float* nbase = ntgt + ((size_t)b * 64 + co0 + q * 4) * 16384 + (size_t)h * 128;
        #pragma unroll
        for (int t = 0; t < 8; ++t)
            #pragma unroll
            for (int r = 0; r < 4; ++r)
                nbase[(size_t)r * 16384 + t * 16 + mm] = msum[t][r] * 0.03125f;
    }
}

extern "C" void kernel_launch(void* const* d_in, const int* in_sizes, int n_in,
                              void* d_out, int out_size, void* d_ws, size_t ws_size,
                              hipStream_t stream) {
    const float* x    = (const float*)d_in[0];
    const float* y    = (const float*)d_in[1];
    const float* wgt  = (const float*)d_in[2];
    const float* bias = (const float*)d_in[3];
    float* out = (float*)d_out;

    crossop_mfma<<<512, 256, 0, stream>>>(x, y, wgt, bias, out);
}